// Round 1
// baseline (828.940 us; speedup 1.0000x reference)
//
#include <hip/hip_runtime.h>
#include <math.h>

#define BB 64
#define SS 2048
#define HH 512
#define KK 1024

__device__ __forceinline__ float fast_tanh(float x) {
    // tanh(x) = 1 - 2/(exp(2x)+1); saturates correctly for |x| large
    float e = __expf(2.0f * x);
    return 1.0f - 2.0f / (e + 1.0f);
}

// K1: q[b*HH+h] = dot(query[b,:], W_q[h,:])  — one wave per output element
__global__ __launch_bounds__(256) void qproj_kernel(
        const float* __restrict__ query,
        const float* __restrict__ Wq,
        float* __restrict__ q_out) {
    int wave = threadIdx.x >> 6;
    int lane = threadIdx.x & 63;
    int o = blockIdx.x * 4 + wave;          // o = b*HH + h
    int b = o >> 9;                          // / HH
    int h = o & (HH - 1);
    const float4* wrow = (const float4*)(Wq + (size_t)h * HH);
    const float4* qrow = (const float4*)(query + (size_t)b * HH);
    float4 w0 = wrow[lane * 2 + 0];
    float4 w1 = wrow[lane * 2 + 1];
    float4 x0 = qrow[lane * 2 + 0];
    float4 x1 = qrow[lane * 2 + 1];
    float acc = w0.x * x0.x + w0.y * x0.y + w0.z * x0.z + w0.w * x0.w
              + w1.x * x1.x + w1.y * x1.y + w1.z * x1.z + w1.w * x1.w;
    #pragma unroll
    for (int off = 32; off > 0; off >>= 1)
        acc += __shfl_down(acc, off, 64);
    if (lane == 0) q_out[o] = acc;
}

// K2: scores[r] = sum_h tanh(q[b,h] + pk[r,h]) * v[h] — one wave per row r = b*SS+s
__global__ __launch_bounds__(256) void score_kernel(
        const float* __restrict__ pk,
        const float* __restrict__ q,
        const float* __restrict__ v,
        float* __restrict__ scores) {
    int wave = threadIdx.x >> 6;
    int lane = threadIdx.x & 63;
    int r = blockIdx.x * 4 + wave;          // r = b*SS + s
    int b = r >> 11;                         // / SS
    const float4* prow = (const float4*)(pk + (size_t)r * HH);
    const float4* qrow = (const float4*)(q + (size_t)b * HH);
    const float4* vrow = (const float4*)v;
    float acc = 0.0f;
    #pragma unroll
    for (int i = 0; i < 2; ++i) {
        float4 p = prow[lane * 2 + i];
        float4 qq = qrow[lane * 2 + i];
        float4 vv = vrow[lane * 2 + i];
        acc += fast_tanh(qq.x + p.x) * vv.x;
        acc += fast_tanh(qq.y + p.y) * vv.y;
        acc += fast_tanh(qq.z + p.z) * vv.z;
        acc += fast_tanh(qq.w + p.w) * vv.w;
    }
    #pragma unroll
    for (int off = 32; off > 0; off >>= 1)
        acc += __shfl_down(acc, off, 64);
    if (lane == 0) scores[r] = acc;
}

// K3: masked softmax over S per b, in place (scores -> alphas). Block per b, 256 thr x 8 elems.
__global__ __launch_bounds__(256) void softmax_kernel(
        float* __restrict__ alphas,
        const int* __restrict__ mask) {
    int b = blockIdx.x;
    int t = threadIdx.x;
    float* row = alphas + (size_t)b * SS;
    const int* mrow = mask + (size_t)b * SS;
    int base = t * 8;

    float4 s0 = *(const float4*)(row + base);
    float4 s1 = *(const float4*)(row + base + 4);
    int4  m0 = *(const int4*)(mrow + base);
    int4  m1 = *(const int4*)(mrow + base + 4);
    float v[8];
    v[0] = m0.x ? s0.x : -INFINITY;
    v[1] = m0.y ? s0.y : -INFINITY;
    v[2] = m0.z ? s0.z : -INFINITY;
    v[3] = m0.w ? s0.w : -INFINITY;
    v[4] = m1.x ? s1.x : -INFINITY;
    v[5] = m1.y ? s1.y : -INFINITY;
    v[6] = m1.z ? s1.z : -INFINITY;
    v[7] = m1.w ? s1.w : -INFINITY;

    __shared__ float redmax[4];
    __shared__ float redsum[4];
    __shared__ float smax, ssum;

    float mx = v[0];
    #pragma unroll
    for (int i = 1; i < 8; ++i) mx = fmaxf(mx, v[i]);
    #pragma unroll
    for (int off = 32; off > 0; off >>= 1)
        mx = fmaxf(mx, __shfl_xor(mx, off, 64));
    if ((t & 63) == 0) redmax[t >> 6] = mx;
    __syncthreads();
    if (t == 0) smax = fmaxf(fmaxf(redmax[0], redmax[1]), fmaxf(redmax[2], redmax[3]));
    __syncthreads();
    mx = smax;

    float e[8];
    float sum = 0.0f;
    #pragma unroll
    for (int i = 0; i < 8; ++i) { e[i] = __expf(v[i] - mx); sum += e[i]; }
    #pragma unroll
    for (int off = 32; off > 0; off >>= 1)
        sum += __shfl_xor(sum, off, 64);
    if ((t & 63) == 0) redsum[t >> 6] = sum;
    __syncthreads();
    if (t == 0) ssum = redsum[0] + redsum[1] + redsum[2] + redsum[3];
    __syncthreads();
    float inv = 1.0f / ssum;

    float4 o0 = make_float4(e[0] * inv, e[1] * inv, e[2] * inv, e[3] * inv);
    float4 o1 = make_float4(e[4] * inv, e[5] * inv, e[6] * inv, e[7] * inv);
    *(float4*)(row + base)     = o0;
    *(float4*)(row + base + 4) = o1;
}

// K4a: zero the context region (d_out is poisoned 0xAA before every launch)
__global__ __launch_bounds__(256) void zero_kernel(float* __restrict__ p, int n) {
    int i = blockIdx.x * 256 + threadIdx.x;
    if (i < n) p[i] = 0.0f;
}

// K4b: context[b,k] += sum_{s in chunk} alpha[b,s] * eh[b,s,k]
// grid (16 s-chunks, 64 b), 256 threads, thread owns float4 of K.
#define SCHUNK 128
__global__ __launch_bounds__(256) void context_kernel(
        const float* __restrict__ eh,
        const float* __restrict__ alphas,
        float* __restrict__ ctx) {
    int chunk = blockIdx.x;
    int b = blockIdx.y;
    int t = threadIdx.x;
    __shared__ float a_sm[SCHUNK];
    if (t < SCHUNK) a_sm[t] = alphas[(size_t)b * SS + chunk * SCHUNK + t];
    __syncthreads();
    const float4* base = (const float4*)(eh + ((size_t)b * SS + (size_t)chunk * SCHUNK) * KK);
    float4 acc = make_float4(0.f, 0.f, 0.f, 0.f);
    #pragma unroll 4
    for (int s = 0; s < SCHUNK; ++s) {
        float a = a_sm[s];
        float4 x = base[(size_t)s * (KK / 4) + t];
        acc.x += a * x.x;
        acc.y += a * x.y;
        acc.z += a * x.z;
        acc.w += a * x.w;
    }
    float* c = ctx + (size_t)b * KK + t * 4;
    atomicAdd(c + 0, acc.x);
    atomicAdd(c + 1, acc.y);
    atomicAdd(c + 2, acc.z);
    atomicAdd(c + 3, acc.w);
}

extern "C" void kernel_launch(void* const* d_in, const int* in_sizes, int n_in,
                              void* d_out, int out_size, void* d_ws, size_t ws_size,
                              hipStream_t stream) {
    const float* query    = (const float*)d_in[0];  // B x 1 x H
    const float* proj_key = (const float*)d_in[1];  // B x S x H
    const float* eh       = (const float*)d_in[2];  // B x S x K
    const int*   mask     = (const int*)  d_in[3];  // B x 1 x S
    const float* Wq       = (const float*)d_in[4];  // H x H
    const float* venergy  = (const float*)d_in[5];  // H

    float* ctx    = (float*)d_out;              // B*K = 65536 floats
    float* alphas = (float*)d_out + BB * KK;    // B*S = 131072 floats

    // Stage q (B*H = 32768 floats) in the context region of d_out; it is
    // consumed by K2 and then zeroed by K4a before context accumulation.
    float* q_tmp = ctx;

    // K1: q projection — (B*H)/4 waves-per-block
    qproj_kernel<<<(BB * HH) / 4, 256, 0, stream>>>(query, Wq, q_tmp);

    // K2: scores (written raw into the alpha region)
    score_kernel<<<(BB * SS) / 4, 256, 0, stream>>>(proj_key, q_tmp, venergy, alphas);

    // K3: masked softmax in place
    softmax_kernel<<<BB, 256, 0, stream>>>(alphas, mask);

    // K4a: zero context
    zero_kernel<<<(BB * KK) / 256, 256, 0, stream>>>(ctx, BB * KK);

    // K4b: context accumulation
    context_kernel<<<dim3(SS / SCHUNK, BB), 256, 0, stream>>>(eh, alphas, ctx);
}